// Round 11
// baseline (592.016 us; speedup 1.0000x reference)
//
#include <hip/hip_runtime.h>
#include <cstdint>
#include <cstddef>

#define IN_DIM  768
#define NNODES  10000
#define MPAD    10112        // 79 * 128
#define NEDGES  80000
#define E_TOT   90000        // edges + self loops
#define HEADS   8
#define HID     256
#define HC      2048         // HEADS*HID
#define NEG_SLOPE 0.2f

// prep_kernel block ranges (256 threads each)
#define CVT_BLK  ((MPAD * IN_DIM / 4) / 256)          // 7584
#define CNT_BLK  ((E_TOT + 255) / 256)                // 352
#define T1_BLK   ((HC / 32) * (IN_DIM / 32))          // 1536
#define T2_BLK   ((HC / 32) * (HC / 32))              // 4096
#define TP_BLK   ((HID / 32) * (HID / 32))            // 64
#define PREP_BLK (CVT_BLK + CNT_BLK + T1_BLK + T2_BLK + TP_BLK)

typedef _Float16 __attribute__((ext_vector_type(8))) f16x8;
typedef float    __attribute__((ext_vector_type(4))) f32x4;

// ---------------------------------------------------------------------------
// edge helpers: edge ids [0,NEDGES) are real edges, [NEDGES,E_TOT) self loops
// ---------------------------------------------------------------------------
__device__ __forceinline__ int edge_src(const int* __restrict__ ei, int e) {
    return (e < NEDGES) ? ei[e] : (e - NEDGES);
}
__device__ __forceinline__ int edge_dst(const int* __restrict__ ei, int e) {
    return (e < NEDGES) ? ei[NEDGES + e] : (e - NEDGES);
}

// ---------------------------------------------------------------------------
// fused preprocessing (R9-proven): cvt + edge count + 3 weight transposes
// ---------------------------------------------------------------------------
__device__ __forceinline__ void tcvt_body(
    const float* __restrict__ W, _Float16* __restrict__ T,
    int K, int N, int bx, int by, int t)
{
    __shared__ float tile[32][33];
    int tx = t & 31, ty = t >> 5;   // 32 x 8
#pragma unroll
    for (int q = 0; q < 4; q++)
        tile[ty + q * 8][tx] = W[(size_t)(by * 32 + ty + q * 8) * N + bx * 32 + tx];
    __syncthreads();
#pragma unroll
    for (int q = 0; q < 4; q++) {
        float v = tile[tx][ty + q * 8];
        T[(size_t)(bx * 32 + ty + q * 8) * K + by * 32 + tx] = (_Float16)v;
    }
}

__global__ __launch_bounds__(256) void prep_kernel(
    const float* __restrict__ x, _Float16* __restrict__ xh,
    const int* __restrict__ ei, int* __restrict__ cnt,
    const float* __restrict__ W1, _Float16* __restrict__ W1t,
    const float* __restrict__ W2, _Float16* __restrict__ W2t,
    const float* __restrict__ Wp, _Float16* __restrict__ Wpt)
{
    int b = blockIdx.x;
    int t = threadIdx.x;
    if (b < CVT_BLK) {
        int i = b * 256 + t;
        size_t e = (size_t)i * 4;
        int r = (int)(e / IN_DIM);
        float4 v = (r < NNODES) ? *(const float4*)(x + e)
                                : make_float4(0.f, 0.f, 0.f, 0.f);
        _Float16 h4[4] = {(_Float16)v.x, (_Float16)v.y, (_Float16)v.z, (_Float16)v.w};
        *(ushort4*)(xh + e) = *(ushort4*)h4;
    } else if (b < CVT_BLK + CNT_BLK) {
        int e = (b - CVT_BLK) * 256 + t;
        if (e < E_TOT) atomicAdd(&cnt[edge_dst(ei, e)], 1);
    } else if (b < CVT_BLK + CNT_BLK + T1_BLK) {
        int idx = b - (CVT_BLK + CNT_BLK);
        tcvt_body(W1, W1t, IN_DIM, HC, idx % (HC / 32), idx / (HC / 32), t);
    } else if (b < CVT_BLK + CNT_BLK + T1_BLK + T2_BLK) {
        int idx = b - (CVT_BLK + CNT_BLK + T1_BLK);
        tcvt_body(W2, W2t, HC, HC, idx % (HC / 32), idx / (HC / 32), t);
    } else {
        int idx = b - (CVT_BLK + CNT_BLK + T1_BLK + T2_BLK);
        tcvt_body(Wp, Wpt, HID, HID, idx % (HID / 32), idx / (HID / 32), t);
    }
}

// ---------------------------------------------------------------------------
// CSR: scan + scatter (count fused into prep_kernel)
// ---------------------------------------------------------------------------
__global__ void scan_kernel(const int* __restrict__ cnt, int* __restrict__ indptr) {
    __shared__ int sums[1024];
    const int CH = 10;
    int t = threadIdx.x;
    int base = t * CH;
    int s = 0;
#pragma unroll
    for (int i = 0; i < CH; i++) { int idx = base + i; if (idx < NNODES) s += cnt[idx]; }
    sums[t] = s;
    __syncthreads();
    for (int off = 1; off < 1024; off <<= 1) {
        int v = (t >= off) ? sums[t - off] : 0;
        __syncthreads();
        sums[t] += v;
        __syncthreads();
    }
    int run = (t == 0) ? 0 : sums[t - 1];
#pragma unroll
    for (int i = 0; i < CH; i++) {
        int idx = base + i;
        if (idx < NNODES) { indptr[idx] = run; run += cnt[idx]; }
    }
    if (t == 0) indptr[NNODES] = E_TOT;
}

__global__ void scatter_kernel(const int* __restrict__ ei, const int* __restrict__ indptr,
                               int* __restrict__ cur, int* __restrict__ sorted) {
    int e = blockIdx.x * 256 + threadIdx.x;
    if (e < E_TOT) {
        int d = edge_dst(ei, e);
        int pos = atomicAdd(&cur[d], 1);
        sorted[indptr[d] + pos] = e;
    }
}

// ---------------------------------------------------------------------------
// fp16 MFMA GEMM:  C[M,Nn] = A[Mpad,K] @ B[Nn,K]^T
// 128x256 tile (two 128-col B tiles per block), BK=32, 256 threads,
// double-buffered LDS (R10-proven structure), 6 global_load_lds/thread/iter.
// Per wave per barrier: 32 MFMA (AITER-measured healthy ratio) vs R10's 16.
// swz=1: XCD remap (requires gridDim.x==8): each XCD owns one 256-col W
// slice (2 MB, L2-resident).
// EPI=0: store fp16 C.  EPI=1: store fp32 relu(C + bias[n]).
// Requires K%32==0, Nn%256==0, grid.y*128 <= Mpad (A rows padded+zeroed).
// ---------------------------------------------------------------------------
template <int EPI>
__global__ __launch_bounds__(256) void mfma_gemm_kernel(
    const _Float16* __restrict__ A, const _Float16* __restrict__ B,
    void* __restrict__ Cout, const float* __restrict__ bias,
    int M, int K, int Nn, int swz)
{
    __shared__ __align__(16) _Float16 sA[2][128 * 32];      // 2 x 8 KB
    __shared__ __align__(16) _Float16 sB[2][2][128 * 32];   // 2 buf x 2 tile x 8 KB

    int t = threadIdx.x;
    int bx = blockIdx.x, by = blockIdx.y;
    if (swz) {                       // gridDim.x == 8 only
        int id = by * 8 + bx;
        bx = id & 7;
        by = id >> 3;
    }
    int row0 = by * 128;
    int col0 = bx * 256;

    // staging: slot s covers (m = s>>2, k-offset = (s&3)*8); each slot = 16B
    int s0 = t, s1 = t + 256;
    int m0 = s0 >> 2, k0 = (s0 & 3) * 8;
    int m1 = s1 >> 2, k1 = (s1 & 3) * 8;
    const _Float16* a0  = A + (size_t)(row0 + m0) * K + k0;
    const _Float16* a1  = A + (size_t)(row0 + m1) * K + k1;
    const _Float16* b00 = B + (size_t)(col0 + m0) * K + k0;        // tile 0
    const _Float16* b01 = B + (size_t)(col0 + m1) * K + k1;
    const _Float16* b10 = B + (size_t)(col0 + 128 + m0) * K + k0;  // tile 1
    const _Float16* b11 = B + (size_t)(col0 + 128 + m1) * K + k1;

    int w = t >> 6, lane = t & 63;
    int wm = (w & 1) * 64, wn = (w >> 1) * 64;
    int fr = lane & 15, quad = lane >> 4;

    auto stage = [&](int kt, int bsel) {
        _Float16* dA0  = &sA[bsel][(w * 64) * 8];        // wave-uniform bases
        _Float16* dA1  = &sA[bsel][(w * 64 + 256) * 8];
        _Float16* dB00 = &sB[bsel][0][(w * 64) * 8];
        _Float16* dB01 = &sB[bsel][0][(w * 64 + 256) * 8];
        _Float16* dB10 = &sB[bsel][1][(w * 64) * 8];
        _Float16* dB11 = &sB[bsel][1][(w * 64 + 256) * 8];
        __builtin_amdgcn_global_load_lds(
            (const __attribute__((address_space(1))) void*)(a0 + kt),
            (__attribute__((address_space(3))) void*)dA0, 16, 0, 0);
        __builtin_amdgcn_global_load_lds(
            (const __attribute__((address_space(1))) void*)(a1 + kt),
            (__attribute__((address_space(3))) void*)dA1, 16, 0, 0);
        __builtin_amdgcn_global_load_lds(
            (const __attribute__((address_space(1))) void*)(b00 + kt),
            (__attribute__((address_space(3))) void*)dB00, 16, 0, 0);
        __builtin_amdgcn_global_load_lds(
            (const __attribute__((address_space(1))) void*)(b01 + kt),
            (__attribute__((address_space(3))) void*)dB01, 16, 0, 0);
        __builtin_amdgcn_global_load_lds(
            (const __attribute__((address_space(1))) void*)(b10 + kt),
            (__attribute__((address_space(3))) void*)dB10, 16, 0, 0);
        __builtin_amdgcn_global_load_lds(
            (const __attribute__((address_space(1))) void*)(b11 + kt),
            (__attribute__((address_space(3))) void*)dB11, 16, 0, 0);
    };

    f32x4 acc[2][4][4];
#pragma unroll
    for (int c = 0; c < 2; c++)
#pragma unroll
        for (int i = 0; i < 4; i++)
#pragma unroll
            for (int j = 0; j < 4; j++) acc[c][i][j] = {0.f, 0.f, 0.f, 0.f};

    const int nIt = K / 32;
    stage(0, 0);
    __syncthreads();                 // tile 0 landed

    for (int it = 0; it < nIt; ++it) {
        int cb = it & 1;
        if (it + 1 < nIt) stage((it + 1) * 32, cb ^ 1);   // prefetch next

        f16x8 fa[4];
#pragma unroll
        for (int i = 0; i < 4; i++)
            fa[i] = *(const f16x8*)&sA[cb][(wm + i * 16 + fr) * 32 + quad * 8];
#pragma unroll
        for (int c = 0; c < 2; c++) {
            f16x8 fb[4];
#pragma unroll
            for (int i = 0; i < 4; i++)
                fb[i] = *(const f16x8*)&sB[cb][c][(wn + i * 16 + fr) * 32 + quad * 8];
#pragma unroll
            for (int i = 0; i < 4; i++)
#pragma unroll
                for (int j = 0; j < 4; j++)
                    acc[c][i][j] = __builtin_amdgcn_mfma_f32_16x16x32_f16(
                        fa[i], fb[j], acc[c][i][j], 0, 0, 0);
        }

        if (it + 1 < nIt) __syncthreads();   // reads of cb done + next tile landed
    }

    // C/D layout (measured m89/m91): col = lane&15, row = quad*4 + reg
#pragma unroll
    for (int c = 0; c < 2; c++) {
        int colc = col0 + c * 128;
        if (EPI == 0) {
            _Float16* C = (_Float16*)Cout;
#pragma unroll
            for (int i = 0; i < 4; i++) {
                int mbase = row0 + wm + i * 16 + quad * 4;
#pragma unroll
                for (int j = 0; j < 4; j++) {
                    int n = colc + wn + j * 16 + fr;
#pragma unroll
                    for (int r = 0; r < 4; r++) {
                        int m = mbase + r;
                        if (m < M) C[(size_t)m * Nn + n] = (_Float16)acc[c][i][j][r];
                    }
                }
            }
        } else {
            float* C = (float*)Cout;
            float bv[4];
#pragma unroll
            for (int j = 0; j < 4; j++) bv[j] = bias[colc + wn + j * 16 + fr];
#pragma unroll
            for (int i = 0; i < 4; i++) {
                int mbase = row0 + wm + i * 16 + quad * 4;
#pragma unroll
                for (int j = 0; j < 4; j++) {
                    int n = colc + wn + j * 16 + fr;
#pragma unroll
                    for (int r = 0; r < 4; r++) {
                        int m = mbase + r;
                        if (m < M) C[(size_t)m * Nn + n] = fmaxf(acc[c][i][j][r] + bv[j], 0.f);
                    }
                }
            }
        }
    }
}

// ---------------------------------------------------------------------------
// per-node attention coefficients from fp16 H: one f16x8 load per lane
// covers a head's 256 channels with 32 lanes.
// ---------------------------------------------------------------------------
__global__ __launch_bounds__(256) void attn_kernel(
    const _Float16* __restrict__ H, const float* __restrict__ a_src,
    const float* __restrict__ a_dst, float* __restrict__ as_out,
    float* __restrict__ ad_out)
{
    int n = blockIdx.x;
    int t = threadIdx.x;
    int h = t >> 5, l = t & 31;
    f16x8 hv = *(const f16x8*)&H[(size_t)n * HC + h * HID + l * 8];
    const float* asp = a_src + h * HID + l * 8;
    const float* adp = a_dst + h * HID + l * 8;
    float sa = 0.f, sd = 0.f;
#pragma unroll
    for (int q = 0; q < 8; q++) {
        float v = (float)hv[q];
        sa = fmaf(v, asp[q], sa);
        sd = fmaf(v, adp[q], sd);
    }
#pragma unroll
    for (int o = 16; o > 0; o >>= 1) {
        sa += __shfl_xor(sa, o, 32);
        sd += __shfl_xor(sd, o, 32);
    }
    if (l == 0) { as_out[n * HEADS + h] = sa; ad_out[n * HEADS + h] = sd; }
}

// ---------------------------------------------------------------------------
// per-dst-node gather aggregation with segment softmax.  H is fp16.
// thread t covers 8 consecutive channels of head t>>5 -> one 16B load/edge.
// MODE 0: elu(sum + b1) -> fp16 [MPAD, HC]
// MODE 1: (mean over heads + b2) -> fp16 [MPAD, HID]   (feeds MFMA proj)
// blocks n >= NNODES just zero-pad (grid = MPAD for both modes).
// ---------------------------------------------------------------------------
template <int MODE>
__global__ __launch_bounds__(256) void agg_kernel(
    const _Float16* __restrict__ H, const float* __restrict__ as_,
    const float* __restrict__ ad_, const float* __restrict__ bias,
    const int* __restrict__ indptr, const int* __restrict__ sorted,
    const int* __restrict__ ei, _Float16* __restrict__ outh)
{
    __shared__ float m8[HEADS], d8[HEADS], adl[HEADS];
    __shared__ int   srcl[64];
    __shared__ float al[64][HEADS];
    __shared__ float red[HC];          // MODE 1 cross-head reduction

    int n = blockIdx.x;
    int t = threadIdx.x;

    if (n >= NNODES) {                 // pad rows for the next MFMA GEMM
        if (MODE == 0) {
            _Float16 z8[8] = {};
            *(f16x8*)&outh[(size_t)n * HC + t * 8] = *(f16x8*)z8;
        } else {
            outh[(size_t)n * HID + t] = (_Float16)0.f;
        }
        return;
    }

    int start = indptr[n];
    int deg = indptr[n + 1] - start;

    if (t < HEADS) adl[t] = ad_[n * HEADS + t];
    __syncthreads();

    int h = t >> 5, l = t & 31;
    float adh = adl[h];

    float mx = -1e30f;
    for (int j = l; j < deg; j += 32) {
        int e = sorted[start + j];
        int s = edge_src(ei, e);
        float v = as_[s * HEADS + h] + adh;
        v = (v >= 0.f) ? v : NEG_SLOPE * v;
        mx = fmaxf(mx, v);
    }
#pragma unroll
    for (int o = 16; o > 0; o >>= 1) mx = fmaxf(mx, __shfl_xor(mx, o, 32));

    float sm = 0.f;
    for (int j = l; j < deg; j += 32) {
        int e = sorted[start + j];
        int s = edge_src(ei, e);
        float v = as_[s * HEADS + h] + adh;
        v = (v >= 0.f) ? v : NEG_SLOPE * v;
        sm += expf(v - mx);
    }
#pragma unroll
    for (int o = 16; o > 0; o >>= 1) sm += __shfl_xor(sm, o, 32);
    if (l == 0) { m8[h] = mx; d8[h] = sm; }

    // gather phase: thread t -> head hh, channels c8..c8+7
    int hh = t >> 5, c8 = (t & 31) * 8;
    const size_t hoff = (size_t)hh * HID + c8;
    float acc[8] = {};
    for (int base = 0; base < deg; base += 64) {
        int cntc = min(64, deg - base);
        __syncthreads();
        if (t < cntc) srcl[t] = edge_src(ei, sorted[start + base + t]);
        __syncthreads();
        {
            int j = t & 63, h0 = t >> 6;
            if (j < cntc) {
#pragma unroll
                for (int q = 0; q < 2; q++) {
                    int hx = h0 + q * 4;
                    float v = as_[srcl[j] * HEADS + hx] + adl[hx];
                    v = (v >= 0.f) ? v : NEG_SLOPE * v;
                    al[j][hx] = expf(v - m8[hx]) / (d8[hx] + 1e-16f);
                }
            }
        }
        __syncthreads();
        for (int jj = 0; jj < cntc; jj++) {
            int s = srcl[jj];
            f16x8 hv = *(const f16x8*)&H[(size_t)s * HC + hoff];
            float a = al[jj][hh];
#pragma unroll
            for (int q = 0; q < 8; q++)
                acc[q] = fmaf(a, (float)hv[q], acc[q]);
        }
    }

    if (MODE == 0) {
        _Float16 o8[8];
#pragma unroll
        for (int q = 0; q < 8; q++) {
            float v = acc[q] + bias[hoff + q];
            v = (v > 0.f) ? v : expm1f(v);          // ELU (alpha=1)
            o8[q] = (_Float16)v;
        }
        *(f16x8*)&outh[(size_t)n * HC + hoff] = *(f16x8*)o8;
    } else {
#pragma unroll
        for (int q = 0; q < 8; q++) red[hoff + q] = acc[q];
        __syncthreads();
        float s = 0.f;
#pragma unroll
        for (int h2 = 0; h2 < HEADS; h2++) s += red[h2 * HID + t];
        outh[(size_t)n * HID + t] = (_Float16)(s * 0.125f + bias[t]);
    }
}

// ---------------------------------------------------------------------------
extern "C" void kernel_launch(void* const* d_in, const int* in_sizes, int n_in,
                              void* d_out, int out_size, void* d_ws, size_t ws_size,
                              hipStream_t stream)
{
    const float* x      = (const float*)d_in[0];
    const int*   ei     = (const int*)  d_in[1];
    const float* W1     = (const float*)d_in[2];
    const float* a_src1 = (const float*)d_in[3];
    const float* a_dst1 = (const float*)d_in[4];
    const float* b1     = (const float*)d_in[5];
    const float* W2     = (const float*)d_in[6];
    const float* a_src2 = (const float*)d_in[7];
    const float* a_dst2 = (const float*)d_in[8];
    const float* b2     = (const float*)d_in[9];
    const float* Wp     = (const float*)d_in[10];
    const float* bp     = (const float*)d_in[11];
    float* out = (float*)d_out;

    char* ws = (char*)d_ws;
    size_t off = 0;
    auto alloc = [&](size_t bytes) -> char* {
        char* p = ws + off;
        off += (bytes + 255) & ~(size_t)255;
        return p;
    };
    _Float16* Hbuf = (_Float16*)alloc((size_t)NNODES * HC * 2);          // 41 MB (H1, then H2)
    _Float16* A2   = (_Float16*)alloc((size_t)MPAD * HC * 2);            // 41.4 MB
    _Float16* W1t  = (_Float16*)alloc((size_t)HC * IN_DIM * 2);          // 3.1 MB
    _Float16* W2t  = (_Float16*)alloc((size_t)HC * HC * 2);              // 8.4 MB
    _Float16* Wpt  = (_Float16*)alloc((size_t)HID * HID * 2);            // 128 KB
    _Float16* xh   = (_Float16*)alloc((size_t)MPAD * IN_DIM * 2);        // 15.5 MB
    _Float16* out2h = (_Float16*)alloc((size_t)MPAD * HID * 2);          // 5.2 MB
    float* asad   = (float*)alloc((size_t)4 * NNODES * HEADS * sizeof(float));
    float* as1 = asad;
    float* ad1 = asad + (size_t)NNODES * HEADS;
    float* as2 = asad + (size_t)2 * NNODES * HEADS;
    float* ad2 = asad + (size_t)3 * NNODES * HEADS;
    int*   cntcur = (int*)alloc((size_t)2 * NNODES * sizeof(int));   // cnt | cur contiguous
    int*   cnt = cntcur;
    int*   cur = cntcur + NNODES;
    int*   indptr = (int*)  alloc((size_t)(NNODES + 1) * sizeof(int));
    int*   sorted = (int*)  alloc((size_t)E_TOT * sizeof(int));

    // --- one memset for cnt+cur, then fused prep (cvt + count + 3 transposes)
    hipMemsetAsync(cntcur, 0, (size_t)2 * NNODES * sizeof(int), stream);
    prep_kernel<<<PREP_BLK, 256, 0, stream>>>(x, xh, ei, cnt,
                                              W1, W1t, W2, W2t, Wp, Wpt);
    scan_kernel<<<1, 1024, 0, stream>>>(cnt, indptr);
    scatter_kernel<<<(E_TOT + 255) / 256, 256, 0, stream>>>(ei, indptr, cur, sorted);

    dim3 gMf(HC / 256, MPAD / 128);   // 8 x 79

    // Layer 1: H1 = x @ W1 (fp16 MFMA, 128x256 tile, dbuf)
    mfma_gemm_kernel<0><<<gMf, 256, 0, stream>>>(xh, W1t, Hbuf, nullptr,
                                                 NNODES, IN_DIM, HC, 1);
    attn_kernel<<<NNODES, 256, 0, stream>>>(Hbuf, a_src1, a_dst1, as1, ad1);
    agg_kernel<0><<<MPAD, 256, 0, stream>>>(Hbuf, as1, ad1, b1, indptr, sorted, ei, A2);

    // Layer 2: H2 = elu_agg @ W2 (fp16 MFMA, 128x256 tile, dbuf)
    mfma_gemm_kernel<0><<<gMf, 256, 0, stream>>>(A2, W2t, Hbuf, nullptr,
                                                 NNODES, HC, HC, 1);
    attn_kernel<<<NNODES, 256, 0, stream>>>(Hbuf, a_src2, a_dst2, as2, ad2);
    agg_kernel<1><<<MPAD, 256, 0, stream>>>(Hbuf, as2, ad2, b2, indptr, sorted, ei, out2h);

    // Projection + ReLU (fp16 MFMA, bias+relu fp32 epilogue)
    dim3 gProj(HID / 256, MPAD / 128);   // 1 x 79
    mfma_gemm_kernel<1><<<gProj, 256, 0, stream>>>(out2h, Wpt, out, bp,
                                                   NNODES, HID, HID, 0);
}

// Round 12
// 473.496 us; speedup vs baseline: 1.2503x; 1.2503x over previous
//
#include <hip/hip_runtime.h>
#include <cstdint>
#include <cstddef>

#define IN_DIM  768
#define NNODES  10000
#define MPAD    10112        // 79 * 128
#define NEDGES  80000
#define E_TOT   90000        // edges + self loops
#define HEADS   8
#define HID     256
#define HC      2048         // HEADS*HID
#define NEG_SLOPE 0.2f
#define BROWS   (HC + 128)   // 2176: Wt rows = 2048 W + 16 attn + 112 zero pad

// prep_kernel block ranges (256 threads each)
#define CVT_BLK  ((MPAD * IN_DIM / 4) / 256)          // 7584
#define CNT_BLK  ((E_TOT + 255) / 256)                // 352
#define T1_BLK   ((HC / 32) * (IN_DIM / 32))          // 1536
#define T2_BLK   ((HC / 32) * (HC / 32))              // 4096
#define TP_BLK   ((HID / 32) * (HID / 32))            // 64
#define WC1_BLK  (16 * (IN_DIM / 128))                // 96
#define WC2_BLK  (16 * (HC / 128))                    // 256
#define Z1_BLK   (112 * IN_DIM / 2048)                // 42
#define Z2_BLK   (112 * HC / 2048)                    // 112
#define PREP_BLK (CVT_BLK + CNT_BLK + T1_BLK + T2_BLK + TP_BLK + \
                  WC1_BLK + WC2_BLK + Z1_BLK + Z2_BLK)

typedef _Float16 __attribute__((ext_vector_type(8))) f16x8;
typedef float    __attribute__((ext_vector_type(4))) f32x4;

// ---------------------------------------------------------------------------
// edge helpers: edge ids [0,NEDGES) are real edges, [NEDGES,E_TOT) self loops
// ---------------------------------------------------------------------------
__device__ __forceinline__ int edge_src(const int* __restrict__ ei, int e) {
    return (e < NEDGES) ? ei[e] : (e - NEDGES);
}
__device__ __forceinline__ int edge_dst(const int* __restrict__ ei, int e) {
    return (e < NEDGES) ? ei[NEDGES + e] : (e - NEDGES);
}

// ---------------------------------------------------------------------------
// prep bodies
// ---------------------------------------------------------------------------
__device__ __forceinline__ void tcvt_body(
    const float* __restrict__ W, _Float16* __restrict__ T,
    int K, int N, int bx, int by, int t)
{
    __shared__ float tile[32][33];
    int tx = t & 31, ty = t >> 5;   // 32 x 8
#pragma unroll
    for (int q = 0; q < 4; q++)
        tile[ty + q * 8][tx] = W[(size_t)(by * 32 + ty + q * 8) * N + bx * 32 + tx];
    __syncthreads();
#pragma unroll
    for (int q = 0; q < 4; q++) {
        float v = tile[tx][ty + q * 8];
        T[(size_t)(bx * 32 + ty + q * 8) * K + by * 32 + tx] = (_Float16)v;
    }
}

// w_comb: T[HC + h16][k] = sum_c W[k][h*HID+c] * a[h][c]   (h = h16&7)
// wave w handles k = ktile*128 + kk (kk = w, w+4, ...), lane-parallel over c.
__device__ __forceinline__ void wcomb_body(
    const float* __restrict__ W, const float* __restrict__ a,
    _Float16* __restrict__ T, int K, int h16, int ktile, int t)
{
    int h = h16 & 7;
    const float* av = a + h * HID;
    int w = t >> 6, lane = t & 63;
    float ar[4];
#pragma unroll
    for (int q = 0; q < 4; q++) ar[q] = av[lane + 64 * q];
    for (int kk = w; kk < 128; kk += 4) {
        int k = ktile * 128 + kk;
        const float* wp = W + (size_t)k * HC + h * HID;
        float s = 0.f;
#pragma unroll
        for (int q = 0; q < 4; q++) s = fmaf(wp[lane + 64 * q], ar[q], s);
#pragma unroll
        for (int o = 32; o > 0; o >>= 1) s += __shfl_xor(s, o, 64);
        if (lane == 0) T[(size_t)(HC + h16) * K + k] = (_Float16)s;
    }
}

__global__ __launch_bounds__(256) void prep_kernel(
    const float* __restrict__ x, _Float16* __restrict__ xh,
    const int* __restrict__ ei, int* __restrict__ cnt,
    const float* __restrict__ W1, _Float16* __restrict__ W1t,
    const float* __restrict__ W2, _Float16* __restrict__ W2t,
    const float* __restrict__ Wp, _Float16* __restrict__ Wpt,
    const float* __restrict__ as1, const float* __restrict__ ad1,
    const float* __restrict__ as2, const float* __restrict__ ad2)
{
    int b = blockIdx.x;
    int t = threadIdx.x;
    int base = 0;
    if (b < (base += CVT_BLK)) {
        int i = b * 256 + t;
        size_t e = (size_t)i * 4;
        int r = (int)(e / IN_DIM);
        float4 v = (r < NNODES) ? *(const float4*)(x + e)
                                : make_float4(0.f, 0.f, 0.f, 0.f);
        _Float16 h4[4] = {(_Float16)v.x, (_Float16)v.y, (_Float16)v.z, (_Float16)v.w};
        *(ushort4*)(xh + e) = *(ushort4*)h4;
        return;
    }
    if (b < (base += CNT_BLK)) {
        int e = (b - (base - CNT_BLK)) * 256 + t;
        if (e < E_TOT) atomicAdd(&cnt[edge_dst(ei, e)], 1);
        return;
    }
    if (b < (base += T1_BLK)) {
        int idx = b - (base - T1_BLK);
        tcvt_body(W1, W1t, IN_DIM, HC, idx % (HC / 32), idx / (HC / 32), t);
        return;
    }
    if (b < (base += T2_BLK)) {
        int idx = b - (base - T2_BLK);
        tcvt_body(W2, W2t, HC, HC, idx % (HC / 32), idx / (HC / 32), t);
        return;
    }
    if (b < (base += TP_BLK)) {
        int idx = b - (base - TP_BLK);
        tcvt_body(Wp, Wpt, HID, HID, idx % (HID / 32), idx / (HID / 32), t);
        return;
    }
    if (b < (base += WC1_BLK)) {
        int idx = b - (base - WC1_BLK);
        int h16 = idx / (IN_DIM / 128), ktile = idx % (IN_DIM / 128);
        wcomb_body(W1, (h16 < 8) ? as1 : ad1, W1t, IN_DIM, h16, ktile, t);
        return;
    }
    if (b < (base += WC2_BLK)) {
        int idx = b - (base - WC2_BLK);
        int h16 = idx / (HC / 128), ktile = idx % (HC / 128);
        wcomb_body(W2, (h16 < 8) ? as2 : ad2, W2t, HC, h16, ktile, t);
        return;
    }
    if (b < (base += Z1_BLK)) {
        int idx = b - (base - Z1_BLK);
        _Float16 z8[8] = {};
        size_t e = (size_t)(HC + 16) * IN_DIM + (size_t)idx * 2048 + t * 8;
        *(f16x8*)&W1t[e] = *(f16x8*)z8;
        return;
    }
    {
        int idx = b - base;
        _Float16 z8[8] = {};
        size_t e = (size_t)(HC + 16) * HC + (size_t)idx * 2048 + t * 8;
        *(f16x8*)&W2t[e] = *(f16x8*)z8;
    }
}

// ---------------------------------------------------------------------------
// CSR: scan + scatter (count fused into prep_kernel)
// ---------------------------------------------------------------------------
__global__ void scan_kernel(const int* __restrict__ cnt, int* __restrict__ indptr) {
    __shared__ int sums[1024];
    const int CH = 10;
    int t = threadIdx.x;
    int base = t * CH;
    int s = 0;
#pragma unroll
    for (int i = 0; i < CH; i++) { int idx = base + i; if (idx < NNODES) s += cnt[idx]; }
    sums[t] = s;
    __syncthreads();
    for (int off = 1; off < 1024; off <<= 1) {
        int v = (t >= off) ? sums[t - off] : 0;
        __syncthreads();
        sums[t] += v;
        __syncthreads();
    }
    int run = (t == 0) ? 0 : sums[t - 1];
#pragma unroll
    for (int i = 0; i < CH; i++) {
        int idx = base + i;
        if (idx < NNODES) { indptr[idx] = run; run += cnt[idx]; }
    }
    if (t == 0) indptr[NNODES] = E_TOT;
}

__global__ void scatter_kernel(const int* __restrict__ ei, const int* __restrict__ indptr,
                               int* __restrict__ cur, int* __restrict__ sorted) {
    int e = blockIdx.x * 256 + threadIdx.x;
    if (e < E_TOT) {
        int d = edge_dst(ei, e);
        int pos = atomicAdd(&cur[d], 1);
        sorted[indptr[d] + pos] = e;
    }
}

// ---------------------------------------------------------------------------
// fp16 MFMA GEMM (R10-proven 128x128 BK=32 dbuf body) + fused attention cols.
// C[M,Nn] = A[Mpad,K] @ B[*,K]^T.  B has Nn + 128 rows for EPI==0 layer
// GEMMs: rows [Nn, Nn+16) are w_comb (attn coefficient vectors), rows
// [Nn+16, Nn+128) zero.  Blocks with col0 >= Nn route their j==0/wn==0
// columns to asad[m][16] (fp32) instead of C.
// EPI=0: fp16 C (+ attn cols).  EPI=1: fp32 relu(C + bias[n]).
// Requires K%32==0, grid.y*128 <= Mpad (A rows padded+zeroed).
// ---------------------------------------------------------------------------
template <int EPI>
__global__ __launch_bounds__(256) void mfma_gemm_kernel(
    const _Float16* __restrict__ A, const _Float16* __restrict__ B,
    void* __restrict__ Cout, const float* __restrict__ bias,
    float* __restrict__ asad, int M, int K, int Nn)
{
    __shared__ __align__(16) _Float16 sA[2][128 * 32];   // 2 x 8 KB
    __shared__ __align__(16) _Float16 sB[2][128 * 32];   // 2 x 8 KB

    int t = threadIdx.x;
    int row0 = blockIdx.y * 128;
    int col0 = blockIdx.x * 128;

    // staging: slot s covers (m = s>>2, k-offset = (s&3)*8); each slot = 16B
    int s0 = t, s1 = t + 256;
    int m0 = s0 >> 2, k0 = (s0 & 3) * 8;
    int m1 = s1 >> 2, k1 = (s1 & 3) * 8;
    const _Float16* a0 = A + (size_t)(row0 + m0) * K + k0;
    const _Float16* a1 = A + (size_t)(row0 + m1) * K + k1;
    const _Float16* b0 = B + (size_t)(col0 + m0) * K + k0;
    const _Float16* b1 = B + (size_t)(col0 + m1) * K + k1;

    int w = t >> 6, lane = t & 63;
    int wm = (w & 1) * 64, wn = (w >> 1) * 64;
    int fr = lane & 15, quad = lane >> 4;

    auto stage = [&](int kt, int bsel) {
        _Float16* dA0 = &sA[bsel][(w * 64) * 8];         // wave-uniform bases
        _Float16* dA1 = &sA[bsel][(w * 64 + 256) * 8];
        _Float16* dB0 = &sB[bsel][(w * 64) * 8];
        _Float16* dB1 = &sB[bsel][(w * 64 + 256) * 8];
        __builtin_amdgcn_global_load_lds(
            (const __attribute__((address_space(1))) void*)(a0 + kt),
            (__attribute__((address_space(3))) void*)dA0, 16, 0, 0);
        __builtin_amdgcn_global_load_lds(
            (const __attribute__((address_space(1))) void*)(a1 + kt),
            (__attribute__((address_space(3))) void*)dA1, 16, 0, 0);
        __builtin_amdgcn_global_load_lds(
            (const __attribute__((address_space(1))) void*)(b0 + kt),
            (__attribute__((address_space(3))) void*)dB0, 16, 0, 0);
        __builtin_amdgcn_global_load_lds(
            (const __attribute__((address_space(1))) void*)(b1 + kt),
            (__attribute__((address_space(3))) void*)dB1, 16, 0, 0);
    };

    f32x4 acc[4][4];
#pragma unroll
    for (int i = 0; i < 4; i++)
#pragma unroll
        for (int j = 0; j < 4; j++) acc[i][j] = {0.f, 0.f, 0.f, 0.f};

    const int nIt = K / 32;
    stage(0, 0);
    __syncthreads();                 // tile 0 landed

    for (int it = 0; it < nIt; ++it) {
        int cb = it & 1;
        if (it + 1 < nIt) stage((it + 1) * 32, cb ^ 1);   // prefetch next

        f16x8 fa[4], fb[4];
#pragma unroll
        for (int i = 0; i < 4; i++) {
            fa[i] = *(const f16x8*)&sA[cb][(wm + i * 16 + fr) * 32 + quad * 8];
            fb[i] = *(const f16x8*)&sB[cb][(wn + i * 16 + fr) * 32 + quad * 8];
        }
#pragma unroll
        for (int i = 0; i < 4; i++)
#pragma unroll
            for (int j = 0; j < 4; j++)
                acc[i][j] = __builtin_amdgcn_mfma_f32_16x16x32_f16(fa[i], fb[j], acc[i][j], 0, 0, 0);

        if (it + 1 < nIt) __syncthreads();   // reads of cb done + next tile landed
    }

    // C/D layout (measured m89/m91): col = lane&15, row = quad*4 + reg
    if (EPI == 0 && col0 >= Nn) {
        // attention-coefficient block: real cols are col0..col0+15 (wn=0, j=0)
        if (wn == 0) {
#pragma unroll
            for (int i = 0; i < 4; i++) {
                int mbase = row0 + wm + i * 16 + quad * 4;
#pragma unroll
                for (int r = 0; r < 4; r++) {
                    int m = mbase + r;
                    if (m < M) asad[(size_t)m * 16 + fr] = acc[i][0][r];
                }
            }
        }
        return;
    }
    if (EPI == 0) {
        _Float16* C = (_Float16*)Cout;
#pragma unroll
        for (int i = 0; i < 4; i++) {
            int mbase = row0 + wm + i * 16 + quad * 4;
#pragma unroll
            for (int j = 0; j < 4; j++) {
                int n = col0 + wn + j * 16 + fr;
#pragma unroll
                for (int r = 0; r < 4; r++) {
                    int m = mbase + r;
                    if (m < M) C[(size_t)m * Nn + n] = (_Float16)acc[i][j][r];
                }
            }
        }
    } else {
        float* C = (float*)Cout;
        float bv[4];
#pragma unroll
        for (int j = 0; j < 4; j++) bv[j] = bias[col0 + wn + j * 16 + fr];
#pragma unroll
        for (int i = 0; i < 4; i++) {
            int mbase = row0 + wm + i * 16 + quad * 4;
#pragma unroll
            for (int j = 0; j < 4; j++) {
                int n = col0 + wn + j * 16 + fr;
#pragma unroll
                for (int r = 0; r < 4; r++) {
                    int m = mbase + r;
                    if (m < M) C[(size_t)m * Nn + n] = fmaxf(acc[i][j][r] + bv[j], 0.f);
                }
            }
        }
    }
}

// ---------------------------------------------------------------------------
// per-dst-node gather aggregation with segment softmax.  H is fp16.
// asad layout: [n][16] fp32 — cols 0..7 = as per head, 8..15 = ad per head.
// MODE 0: elu(sum + b1) -> fp16 [MPAD, HC]
// MODE 1: (mean over heads + b2) -> fp16 [MPAD, HID]   (feeds MFMA proj)
// blocks n >= NNODES just zero-pad (grid = MPAD for both modes).
// ---------------------------------------------------------------------------
template <int MODE>
__global__ __launch_bounds__(256) void agg_kernel(
    const _Float16* __restrict__ H, const float* __restrict__ asad,
    const float* __restrict__ bias,
    const int* __restrict__ indptr, const int* __restrict__ sorted,
    const int* __restrict__ ei, _Float16* __restrict__ outh)
{
    __shared__ float m8[HEADS], d8[HEADS], adl[HEADS];
    __shared__ int   srcl[64];
    __shared__ float al[64][HEADS];
    __shared__ float red[HC];          // MODE 1 cross-head reduction

    int n = blockIdx.x;
    int t = threadIdx.x;

    if (n >= NNODES) {                 // pad rows for the next MFMA GEMM
        if (MODE == 0) {
            _Float16 z8[8] = {};
            *(f16x8*)&outh[(size_t)n * HC + t * 8] = *(f16x8*)z8;
        } else {
            outh[(size_t)n * HID + t] = (_Float16)0.f;
        }
        return;
    }

    int start = indptr[n];
    int deg = indptr[n + 1] - start;

    if (t < HEADS) adl[t] = asad[(size_t)n * 16 + 8 + t];
    __syncthreads();

    int h = t >> 5, l = t & 31;
    float adh = adl[h];

    float mx = -1e30f;
    for (int j = l; j < deg; j += 32) {
        int e = sorted[start + j];
        int s = edge_src(ei, e);
        float v = asad[(size_t)s * 16 + h] + adh;
        v = (v >= 0.f) ? v : NEG_SLOPE * v;
        mx = fmaxf(mx, v);
    }
#pragma unroll
    for (int o = 16; o > 0; o >>= 1) mx = fmaxf(mx, __shfl_xor(mx, o, 32));

    float sm = 0.f;
    for (int j = l; j < deg; j += 32) {
        int e = sorted[start + j];
        int s = edge_src(ei, e);
        float v = asad[(size_t)s * 16 + h] + adh;
        v = (v >= 0.f) ? v : NEG_SLOPE * v;
        sm += expf(v - mx);
    }
#pragma unroll
    for (int o = 16; o > 0; o >>= 1) sm += __shfl_xor(sm, o, 32);
    if (l == 0) { m8[h] = mx; d8[h] = sm; }

    // gather phase: thread t -> head hh, channels c8..c8+7
    int hh = t >> 5, c8 = (t & 31) * 8;
    const size_t hoff = (size_t)hh * HID + c8;
    float acc[8] = {};
    for (int base = 0; base < deg; base += 64) {
        int cntc = min(64, deg - base);
        __syncthreads();
        if (t < cntc) srcl[t] = edge_src(ei, sorted[start + base + t]);
        __syncthreads();
        {
            int j = t & 63, h0 = t >> 6;
            if (j < cntc) {
#pragma unroll
                for (int q = 0; q < 2; q++) {
                    int hx = h0 + q * 4;
                    float v = asad[(size_t)srcl[j] * 16 + hx] + adl[hx];
                    v = (v >= 0.f) ? v : NEG_SLOPE * v;
                    al[j][hx] = expf(v - m8[hx]) / (d8[hx] + 1e-16f);
                }
            }
        }
        __syncthreads();
        for (int jj = 0; jj < cntc; jj++) {
            int s = srcl[jj];
            f16x8 hv = *(const f16x8*)&H[(size_t)s * HC + hoff];
            float a = al[jj][hh];
#pragma unroll
            for (int q = 0; q < 8; q++)
                acc[q] = fmaf(a, (float)hv[q], acc[q]);
        }
    }

    if (MODE == 0) {
        _Float16 o8[8];
#pragma unroll
        for (int q = 0; q < 8; q++) {
            float v = acc[q] + bias[hoff + q];
            v = (v > 0.f) ? v : expm1f(v);          // ELU (alpha=1)
            o8[q] = (_Float16)v;
        }
        *(f16x8*)&outh[(size_t)n * HC + hoff] = *(f16x8*)o8;
    } else {
#pragma unroll
        for (int q = 0; q < 8; q++) red[hoff + q] = acc[q];
        __syncthreads();
        float s = 0.f;
#pragma unroll
        for (int h2 = 0; h2 < HEADS; h2++) s += red[h2 * HID + t];
        outh[(size_t)n * HID + t] = (_Float16)(s * 0.125f + bias[t]);
    }
}

// ---------------------------------------------------------------------------
extern "C" void kernel_launch(void* const* d_in, const int* in_sizes, int n_in,
                              void* d_out, int out_size, void* d_ws, size_t ws_size,
                              hipStream_t stream)
{
    const float* x      = (const float*)d_in[0];
    const int*   ei     = (const int*)  d_in[1];
    const float* W1     = (const float*)d_in[2];
    const float* a_src1 = (const float*)d_in[3];
    const float* a_dst1 = (const float*)d_in[4];
    const float* b1     = (const float*)d_in[5];
    const float* W2     = (const float*)d_in[6];
    const float* a_src2 = (const float*)d_in[7];
    const float* a_dst2 = (const float*)d_in[8];
    const float* b2     = (const float*)d_in[9];
    const float* Wp     = (const float*)d_in[10];
    const float* bp     = (const float*)d_in[11];
    float* out = (float*)d_out;

    char* ws = (char*)d_ws;
    size_t off = 0;
    auto alloc = [&](size_t bytes) -> char* {
        char* p = ws + off;
        off += (bytes + 255) & ~(size_t)255;
        return p;
    };
    _Float16* Hbuf = (_Float16*)alloc((size_t)NNODES * HC * 2);          // 41 MB (H1, then H2)
    _Float16* A2   = (_Float16*)alloc((size_t)MPAD * HC * 2);            // 41.4 MB
    _Float16* W1t  = (_Float16*)alloc((size_t)BROWS * IN_DIM * 2);       // 3.2 MB
    _Float16* W2t  = (_Float16*)alloc((size_t)BROWS * HC * 2);           // 8.9 MB
    _Float16* Wpt  = (_Float16*)alloc((size_t)HID * HID * 2);            // 128 KB
    _Float16* xh   = (_Float16*)alloc((size_t)MPAD * IN_DIM * 2);        // 15.5 MB
    _Float16* out2h = (_Float16*)alloc((size_t)MPAD * HID * 2);          // 5.2 MB
    float* asad1 = (float*)alloc((size_t)MPAD * 16 * sizeof(float));     // 647 KB
    float* asad2 = (float*)alloc((size_t)MPAD * 16 * sizeof(float));
    int*   cntcur = (int*)alloc((size_t)2 * NNODES * sizeof(int));   // cnt | cur contiguous
    int*   cnt = cntcur;
    int*   cur = cntcur + NNODES;
    int*   indptr = (int*)  alloc((size_t)(NNODES + 1) * sizeof(int));
    int*   sorted = (int*)  alloc((size_t)E_TOT * sizeof(int));

    // --- one memset for cnt+cur, then fused prep
    //     (cvt + count + 3 transposes + w_comb attn vectors + pad zeroing)
    hipMemsetAsync(cntcur, 0, (size_t)2 * NNODES * sizeof(int), stream);
    prep_kernel<<<PREP_BLK, 256, 0, stream>>>(x, xh, ei, cnt,
                                              W1, W1t, W2, W2t, Wp, Wpt,
                                              a_src1, a_dst1, a_src2, a_dst2);
    scan_kernel<<<1, 1024, 0, stream>>>(cnt, indptr);
    scatter_kernel<<<(E_TOT + 255) / 256, 256, 0, stream>>>(ei, indptr, cur, sorted);

    dim3 gMf(HC / 128 + 1, MPAD / 128);   // 17 x 79 (last col block = attn)

    // Layer 1: H1 = x @ W1 (fp16 MFMA, BK=32, dbuf) + fused as/ad columns
    mfma_gemm_kernel<0><<<gMf, 256, 0, stream>>>(xh, W1t, Hbuf, nullptr,
                                                 asad1, NNODES, IN_DIM, HC);
    agg_kernel<0><<<MPAD, 256, 0, stream>>>(Hbuf, asad1, b1, indptr, sorted, ei, A2);

    // Layer 2: H2 = elu_agg @ W2 (fp16 MFMA, BK=32, dbuf) + fused as/ad columns
    mfma_gemm_kernel<0><<<gMf, 256, 0, stream>>>(A2, W2t, Hbuf, nullptr,
                                                 asad2, NNODES, HC, HC);
    agg_kernel<1><<<MPAD, 256, 0, stream>>>(Hbuf, asad2, b2, indptr, sorted, ei, out2h);

    // Projection + ReLU (fp16 MFMA, bias+relu fp32 epilogue)
    dim3 gProj(HID / 128, MPAD / 128);   // 2 x 79
    mfma_gemm_kernel<1><<<gProj, 256, 0, stream>>>(out2h, Wpt, out, bp,
                                                   nullptr, NNODES, HID, HID);
}

// Round 13
// 452.754 us; speedup vs baseline: 1.3076x; 1.0458x over previous
//
#include <hip/hip_runtime.h>
#include <cstdint>
#include <cstddef>

#define IN_DIM  768
#define NNODES  10000
#define MPAD    10112        // 79 * 128
#define NEDGES  80000
#define E_TOT   90000        // edges + self loops
#define HEADS   8
#define HID     256
#define HC      2048         // HEADS*HID
#define NEG_SLOPE 0.2f

// prep_kernel block ranges (256 threads each)
#define CVT_BLK  ((MPAD * IN_DIM / 4) / 256)          // 7584
#define CNT_BLK  ((E_TOT + 255) / 256)                // 352
#define T1_BLK   ((HC / 32) * (IN_DIM / 32))          // 1536
#define T2_BLK   ((HC / 32) * (HC / 32))              // 4096
#define TP_BLK   ((HID / 32) * (HID / 32))            // 64
#define PREP_BLK (CVT_BLK + CNT_BLK + T1_BLK + T2_BLK + TP_BLK)

typedef _Float16 __attribute__((ext_vector_type(8))) f16x8;
typedef float    __attribute__((ext_vector_type(4))) f32x4;

// ---------------------------------------------------------------------------
// edge helpers: edge ids [0,NEDGES) are real edges, [NEDGES,E_TOT) self loops
// ---------------------------------------------------------------------------
__device__ __forceinline__ int edge_src(const int* __restrict__ ei, int e) {
    return (e < NEDGES) ? ei[e] : (e - NEDGES);
}
__device__ __forceinline__ int edge_dst(const int* __restrict__ ei, int e) {
    return (e < NEDGES) ? ei[NEDGES + e] : (e - NEDGES);
}

// ---------------------------------------------------------------------------
// fused preprocessing (R9-proven): cvt + edge count + 3 weight transposes
// ---------------------------------------------------------------------------
__device__ __forceinline__ void tcvt_body(
    const float* __restrict__ W, _Float16* __restrict__ T,
    int K, int N, int bx, int by, int t)
{
    __shared__ float tile[32][33];
    int tx = t & 31, ty = t >> 5;   // 32 x 8
#pragma unroll
    for (int q = 0; q < 4; q++)
        tile[ty + q * 8][tx] = W[(size_t)(by * 32 + ty + q * 8) * N + bx * 32 + tx];
    __syncthreads();
#pragma unroll
    for (int q = 0; q < 4; q++) {
        float v = tile[tx][ty + q * 8];
        T[(size_t)(bx * 32 + ty + q * 8) * K + by * 32 + tx] = (_Float16)v;
    }
}

__global__ __launch_bounds__(256) void prep_kernel(
    const float* __restrict__ x, _Float16* __restrict__ xh,
    const int* __restrict__ ei, int* __restrict__ cnt,
    const float* __restrict__ W1, _Float16* __restrict__ W1t,
    const float* __restrict__ W2, _Float16* __restrict__ W2t,
    const float* __restrict__ Wp, _Float16* __restrict__ Wpt)
{
    int b = blockIdx.x;
    int t = threadIdx.x;
    if (b < CVT_BLK) {
        int i = b * 256 + t;
        size_t e = (size_t)i * 4;
        int r = (int)(e / IN_DIM);
        float4 v = (r < NNODES) ? *(const float4*)(x + e)
                                : make_float4(0.f, 0.f, 0.f, 0.f);
        _Float16 h4[4] = {(_Float16)v.x, (_Float16)v.y, (_Float16)v.z, (_Float16)v.w};
        *(ushort4*)(xh + e) = *(ushort4*)h4;
    } else if (b < CVT_BLK + CNT_BLK) {
        int e = (b - CVT_BLK) * 256 + t;
        if (e < E_TOT) atomicAdd(&cnt[edge_dst(ei, e)], 1);
    } else if (b < CVT_BLK + CNT_BLK + T1_BLK) {
        int idx = b - (CVT_BLK + CNT_BLK);
        tcvt_body(W1, W1t, IN_DIM, HC, idx % (HC / 32), idx / (HC / 32), t);
    } else if (b < CVT_BLK + CNT_BLK + T1_BLK + T2_BLK) {
        int idx = b - (CVT_BLK + CNT_BLK + T1_BLK);
        tcvt_body(W2, W2t, HC, HC, idx % (HC / 32), idx / (HC / 32), t);
    } else {
        int idx = b - (CVT_BLK + CNT_BLK + T1_BLK + T2_BLK);
        tcvt_body(Wp, Wpt, HID, HID, idx % (HID / 32), idx / (HID / 32), t);
    }
}

// ---------------------------------------------------------------------------
// CSR: scan + scatter (count fused into prep_kernel)
// ---------------------------------------------------------------------------
__global__ void scan_kernel(const int* __restrict__ cnt, int* __restrict__ indptr) {
    __shared__ int sums[1024];
    const int CH = 10;
    int t = threadIdx.x;
    int base = t * CH;
    int s = 0;
#pragma unroll
    for (int i = 0; i < CH; i++) { int idx = base + i; if (idx < NNODES) s += cnt[idx]; }
    sums[t] = s;
    __syncthreads();
    for (int off = 1; off < 1024; off <<= 1) {
        int v = (t >= off) ? sums[t - off] : 0;
        __syncthreads();
        sums[t] += v;
        __syncthreads();
    }
    int run = (t == 0) ? 0 : sums[t - 1];
#pragma unroll
    for (int i = 0; i < CH; i++) {
        int idx = base + i;
        if (idx < NNODES) { indptr[idx] = run; run += cnt[idx]; }
    }
    if (t == 0) indptr[NNODES] = E_TOT;
}

__global__ void scatter_kernel(const int* __restrict__ ei, const int* __restrict__ indptr,
                               int* __restrict__ cur, int* __restrict__ sorted) {
    int e = blockIdx.x * 256 + threadIdx.x;
    if (e < E_TOT) {
        int d = edge_dst(ei, e);
        int pos = atomicAdd(&cur[d], 1);
        sorted[indptr[d] + pos] = e;
    }
}

// ---------------------------------------------------------------------------
// fp16 MFMA GEMM:  C[M,Nn] = A[Mpad,K] @ B[Nn,K]^T
// 128x128 tile, BK=32, 256 threads — R10-proven double-buffered body
// (best measured: GEMM2 ~126 us, MfmaUtil 29.5%).
// swz=1: XCD remap (requires gridDim.x==16).
// EPI=0: store fp16 C.  EPI=1: store fp32 relu(C + bias[n]).
// Requires K%32==0, Nn%128==0, grid.y*128 <= Mpad (A rows padded+zeroed).
// ---------------------------------------------------------------------------
template <int EPI>
__global__ __launch_bounds__(256) void mfma_gemm_kernel(
    const _Float16* __restrict__ A, const _Float16* __restrict__ B,
    void* __restrict__ Cout, const float* __restrict__ bias,
    int M, int K, int Nn, int swz)
{
    __shared__ __align__(16) _Float16 sA[2][128 * 32];   // 2 x 8 KB
    __shared__ __align__(16) _Float16 sB[2][128 * 32];   // 2 x 8 KB

    int t = threadIdx.x;
    int bx = blockIdx.x, by = blockIdx.y;
    if (swz) {                       // gridDim.x == 16 only
        int id = by * 16 + bx;
        int xcd = id & 7, slot = id >> 3;
        bx = 2 * xcd + (slot & 1);
        by = slot >> 1;
    }
    int row0 = by * 128;
    int col0 = bx * 128;

    // staging: slot s covers (m = s>>2, k-offset = (s&3)*8); each slot = 16B
    int s0 = t, s1 = t + 256;
    int m0 = s0 >> 2, k0 = (s0 & 3) * 8;
    int m1 = s1 >> 2, k1 = (s1 & 3) * 8;
    const _Float16* a0 = A + (size_t)(row0 + m0) * K + k0;
    const _Float16* a1 = A + (size_t)(row0 + m1) * K + k1;
    const _Float16* b0 = B + (size_t)(col0 + m0) * K + k0;
    const _Float16* b1 = B + (size_t)(col0 + m1) * K + k1;

    int w = t >> 6, lane = t & 63;
    int wm = (w & 1) * 64, wn = (w >> 1) * 64;
    int fr = lane & 15, quad = lane >> 4;

    auto stage = [&](int kt, int bsel) {
        _Float16* dA0 = &sA[bsel][(w * 64) * 8];         // wave-uniform bases
        _Float16* dA1 = &sA[bsel][(w * 64 + 256) * 8];
        _Float16* dB0 = &sB[bsel][(w * 64) * 8];
        _Float16* dB1 = &sB[bsel][(w * 64 + 256) * 8];
        __builtin_amdgcn_global_load_lds(
            (const __attribute__((address_space(1))) void*)(a0 + kt),
            (__attribute__((address_space(3))) void*)dA0, 16, 0, 0);
        __builtin_amdgcn_global_load_lds(
            (const __attribute__((address_space(1))) void*)(a1 + kt),
            (__attribute__((address_space(3))) void*)dA1, 16, 0, 0);
        __builtin_amdgcn_global_load_lds(
            (const __attribute__((address_space(1))) void*)(b0 + kt),
            (__attribute__((address_space(3))) void*)dB0, 16, 0, 0);
        __builtin_amdgcn_global_load_lds(
            (const __attribute__((address_space(1))) void*)(b1 + kt),
            (__attribute__((address_space(3))) void*)dB1, 16, 0, 0);
    };

    f32x4 acc[4][4];
#pragma unroll
    for (int i = 0; i < 4; i++)
#pragma unroll
        for (int j = 0; j < 4; j++) acc[i][j] = {0.f, 0.f, 0.f, 0.f};

    const int nIt = K / 32;
    stage(0, 0);
    __syncthreads();                 // tile 0 landed

    for (int it = 0; it < nIt; ++it) {
        int cb = it & 1;
        if (it + 1 < nIt) stage((it + 1) * 32, cb ^ 1);   // prefetch next

        f16x8 fa[4], fb[4];
#pragma unroll
        for (int i = 0; i < 4; i++) {
            fa[i] = *(const f16x8*)&sA[cb][(wm + i * 16 + fr) * 32 + quad * 8];
            fb[i] = *(const f16x8*)&sB[cb][(wn + i * 16 + fr) * 32 + quad * 8];
        }
#pragma unroll
        for (int i = 0; i < 4; i++)
#pragma unroll
            for (int j = 0; j < 4; j++)
                acc[i][j] = __builtin_amdgcn_mfma_f32_16x16x32_f16(fa[i], fb[j], acc[i][j], 0, 0, 0);

        if (it + 1 < nIt) __syncthreads();   // reads of cb done + next tile landed
    }

    // C/D layout (measured m89/m91): col = lane&15, row = quad*4 + reg
    if (EPI == 0) {
        _Float16* C = (_Float16*)Cout;
#pragma unroll
        for (int i = 0; i < 4; i++) {
            int mbase = row0 + wm + i * 16 + quad * 4;
#pragma unroll
            for (int j = 0; j < 4; j++) {
                int n = col0 + wn + j * 16 + fr;
#pragma unroll
                for (int r = 0; r < 4; r++) {
                    int m = mbase + r;
                    if (m < M) C[(size_t)m * Nn + n] = (_Float16)acc[i][j][r];
                }
            }
        }
    } else {
        float* C = (float*)Cout;
        float bv[4];
#pragma unroll
        for (int j = 0; j < 4; j++) bv[j] = bias[col0 + wn + j * 16 + fr];
#pragma unroll
        for (int i = 0; i < 4; i++) {
            int mbase = row0 + wm + i * 16 + quad * 4;
#pragma unroll
            for (int j = 0; j < 4; j++) {
                int n = col0 + wn + j * 16 + fr;
#pragma unroll
                for (int r = 0; r < 4; r++) {
                    int m = mbase + r;
                    if (m < M) C[(size_t)m * Nn + n] = fmaxf(acc[i][j][r] + bv[j], 0.f);
                }
            }
        }
    }
}

// ---------------------------------------------------------------------------
// per-node attention coefficients from fp16 H: one f16x8 load per lane
// covers a head's 256 channels with 32 lanes.
// ---------------------------------------------------------------------------
__global__ __launch_bounds__(256) void attn_kernel(
    const _Float16* __restrict__ H, const float* __restrict__ a_src,
    const float* __restrict__ a_dst, float* __restrict__ as_out,
    float* __restrict__ ad_out)
{
    int n = blockIdx.x;
    int t = threadIdx.x;
    int h = t >> 5, l = t & 31;
    f16x8 hv = *(const f16x8*)&H[(size_t)n * HC + h * HID + l * 8];
    const float* asp = a_src + h * HID + l * 8;
    const float* adp = a_dst + h * HID + l * 8;
    float sa = 0.f, sd = 0.f;
#pragma unroll
    for (int q = 0; q < 8; q++) {
        float v = (float)hv[q];
        sa = fmaf(v, asp[q], sa);
        sd = fmaf(v, adp[q], sd);
    }
#pragma unroll
    for (int o = 16; o > 0; o >>= 1) {
        sa += __shfl_xor(sa, o, 32);
        sd += __shfl_xor(sd, o, 32);
    }
    if (l == 0) { as_out[n * HEADS + h] = sa; ad_out[n * HEADS + h] = sd; }
}

// ---------------------------------------------------------------------------
// per-dst-node gather aggregation with segment softmax.  H is fp16.
// thread t covers 8 consecutive channels of head t>>5 -> one 16B load/edge.
// Gather loop is 4-deep unrolled: 4 independent loads in flight per thread
// (latency hiding); FMAs applied in original edge order -> bit-identical
// accumulation vs the R10 rolled loop.
// MODE 0: elu(sum + b1) -> fp16 [MPAD, HC]
// MODE 1: (mean over heads + b2) -> fp16 [MPAD, HID]   (feeds MFMA proj)
// blocks n >= NNODES just zero-pad (grid = MPAD for both modes).
// ---------------------------------------------------------------------------
template <int MODE>
__global__ __launch_bounds__(256) void agg_kernel(
    const _Float16* __restrict__ H, const float* __restrict__ as_,
    const float* __restrict__ ad_, const float* __restrict__ bias,
    const int* __restrict__ indptr, const int* __restrict__ sorted,
    const int* __restrict__ ei, _Float16* __restrict__ outh)
{
    __shared__ float m8[HEADS], d8[HEADS], adl[HEADS];
    __shared__ int   srcl[64];
    __shared__ float al[64][HEADS];
    __shared__ float red[HC];          // MODE 1 cross-head reduction

    int n = blockIdx.x;
    int t = threadIdx.x;

    if (n >= NNODES) {                 // pad rows for the next MFMA GEMM
        if (MODE == 0) {
            _Float16 z8[8] = {};
            *(f16x8*)&outh[(size_t)n * HC + t * 8] = *(f16x8*)z8;
        } else {
            outh[(size_t)n * HID + t] = (_Float16)0.f;
        }
        return;
    }

    int start = indptr[n];
    int deg = indptr[n + 1] - start;

    if (t < HEADS) adl[t] = ad_[n * HEADS + t];
    __syncthreads();

    int h = t >> 5, l = t & 31;
    float adh = adl[h];

    float mx = -1e30f;
    for (int j = l; j < deg; j += 32) {
        int e = sorted[start + j];
        int s = edge_src(ei, e);
        float v = as_[s * HEADS + h] + adh;
        v = (v >= 0.f) ? v : NEG_SLOPE * v;
        mx = fmaxf(mx, v);
    }
#pragma unroll
    for (int o = 16; o > 0; o >>= 1) mx = fmaxf(mx, __shfl_xor(mx, o, 32));

    float sm = 0.f;
    for (int j = l; j < deg; j += 32) {
        int e = sorted[start + j];
        int s = edge_src(ei, e);
        float v = as_[s * HEADS + h] + adh;
        v = (v >= 0.f) ? v : NEG_SLOPE * v;
        sm += expf(v - mx);
    }
#pragma unroll
    for (int o = 16; o > 0; o >>= 1) sm += __shfl_xor(sm, o, 32);
    if (l == 0) { m8[h] = mx; d8[h] = sm; }

    // gather phase: thread t -> head hh, channels c8..c8+7
    int hh = t >> 5, c8 = (t & 31) * 8;
    const size_t hoff = (size_t)hh * HID + c8;
    float acc[8] = {};
    for (int base = 0; base < deg; base += 64) {
        int cntc = min(64, deg - base);
        __syncthreads();
        if (t < cntc) srcl[t] = edge_src(ei, sorted[start + base + t]);
        __syncthreads();
        {
            int j = t & 63, h0 = t >> 6;
            if (j < cntc) {
#pragma unroll
                for (int q = 0; q < 2; q++) {
                    int hx = h0 + q * 4;
                    float v = as_[srcl[j] * HEADS + hx] + adl[hx];
                    v = (v >= 0.f) ? v : NEG_SLOPE * v;
                    al[j][hx] = expf(v - m8[hx]) / (d8[hx] + 1e-16f);
                }
            }
        }
        __syncthreads();
        int jj = 0;
        for (; jj + 3 < cntc; jj += 4) {
            int sx0 = srcl[jj + 0], sx1 = srcl[jj + 1];
            int sx2 = srcl[jj + 2], sx3 = srcl[jj + 3];
            f16x8 h0v = *(const f16x8*)&H[(size_t)sx0 * HC + hoff];
            f16x8 h1v = *(const f16x8*)&H[(size_t)sx1 * HC + hoff];
            f16x8 h2v = *(const f16x8*)&H[(size_t)sx2 * HC + hoff];
            f16x8 h3v = *(const f16x8*)&H[(size_t)sx3 * HC + hoff];
            float a0 = al[jj + 0][hh], a1 = al[jj + 1][hh];
            float a2 = al[jj + 2][hh], a3 = al[jj + 3][hh];
#pragma unroll
            for (int q = 0; q < 8; q++) acc[q] = fmaf(a0, (float)h0v[q], acc[q]);
#pragma unroll
            for (int q = 0; q < 8; q++) acc[q] = fmaf(a1, (float)h1v[q], acc[q]);
#pragma unroll
            for (int q = 0; q < 8; q++) acc[q] = fmaf(a2, (float)h2v[q], acc[q]);
#pragma unroll
            for (int q = 0; q < 8; q++) acc[q] = fmaf(a3, (float)h3v[q], acc[q]);
        }
        for (; jj < cntc; jj++) {
            int s = srcl[jj];
            f16x8 hv = *(const f16x8*)&H[(size_t)s * HC + hoff];
            float a = al[jj][hh];
#pragma unroll
            for (int q = 0; q < 8; q++)
                acc[q] = fmaf(a, (float)hv[q], acc[q]);
        }
    }

    if (MODE == 0) {
        _Float16 o8[8];
#pragma unroll
        for (int q = 0; q < 8; q++) {
            float v = acc[q] + bias[hoff + q];
            v = (v > 0.f) ? v : expm1f(v);          // ELU (alpha=1)
            o8[q] = (_Float16)v;
        }
        *(f16x8*)&outh[(size_t)n * HC + hoff] = *(f16x8*)o8;
    } else {
#pragma unroll
        for (int q = 0; q < 8; q++) red[hoff + q] = acc[q];
        __syncthreads();
        float s = 0.f;
#pragma unroll
        for (int h2 = 0; h2 < HEADS; h2++) s += red[h2 * HID + t];
        outh[(size_t)n * HID + t] = (_Float16)(s * 0.125f + bias[t]);
    }
}

// ---------------------------------------------------------------------------
extern "C" void kernel_launch(void* const* d_in, const int* in_sizes, int n_in,
                              void* d_out, int out_size, void* d_ws, size_t ws_size,
                              hipStream_t stream)
{
    const float* x      = (const float*)d_in[0];
    const int*   ei     = (const int*)  d_in[1];
    const float* W1     = (const float*)d_in[2];
    const float* a_src1 = (const float*)d_in[3];
    const float* a_dst1 = (const float*)d_in[4];
    const float* b1     = (const float*)d_in[5];
    const float* W2     = (const float*)d_in[6];
    const float* a_src2 = (const float*)d_in[7];
    const float* a_dst2 = (const float*)d_in[8];
    const float* b2     = (const float*)d_in[9];
    const float* Wp     = (const float*)d_in[10];
    const float* bp     = (const float*)d_in[11];
    float* out = (float*)d_out;

    char* ws = (char*)d_ws;
    size_t off = 0;
    auto alloc = [&](size_t bytes) -> char* {
        char* p = ws + off;
        off += (bytes + 255) & ~(size_t)255;
        return p;
    };
    _Float16* Hbuf = (_Float16*)alloc((size_t)NNODES * HC * 2);          // 41 MB (H1, then H2)
    _Float16* A2   = (_Float16*)alloc((size_t)MPAD * HC * 2);            // 41.4 MB
    _Float16* W1t  = (_Float16*)alloc((size_t)HC * IN_DIM * 2);          // 3.1 MB
    _Float16* W2t  = (_Float16*)alloc((size_t)HC * HC * 2);              // 8.4 MB
    _Float16* Wpt  = (_Float16*)alloc((size_t)HID * HID * 2);            // 128 KB
    _Float16* xh   = (_Float16*)alloc((size_t)MPAD * IN_DIM * 2);        // 15.5 MB
    _Float16* out2h = (_Float16*)alloc((size_t)MPAD * HID * 2);          // 5.2 MB
    float* asad   = (float*)alloc((size_t)4 * NNODES * HEADS * sizeof(float));
    float* as1 = asad;
    float* ad1 = asad + (size_t)NNODES * HEADS;
    float* as2 = asad + (size_t)2 * NNODES * HEADS;
    float* ad2 = asad + (size_t)3 * NNODES * HEADS;
    int*   cntcur = (int*)alloc((size_t)2 * NNODES * sizeof(int));   // cnt | cur contiguous
    int*   cnt = cntcur;
    int*   cur = cntcur + NNODES;
    int*   indptr = (int*)  alloc((size_t)(NNODES + 1) * sizeof(int));
    int*   sorted = (int*)  alloc((size_t)E_TOT * sizeof(int));

    // --- one memset for cnt+cur, then fused prep (cvt + count + 3 transposes)
    hipMemsetAsync(cntcur, 0, (size_t)2 * NNODES * sizeof(int), stream);
    prep_kernel<<<PREP_BLK, 256, 0, stream>>>(x, xh, ei, cnt,
                                              W1, W1t, W2, W2t, Wp, Wpt);
    scan_kernel<<<1, 1024, 0, stream>>>(cnt, indptr);
    scatter_kernel<<<(E_TOT + 255) / 256, 256, 0, stream>>>(ei, indptr, cur, sorted);

    dim3 gMf(HC / 128, MPAD / 128);   // 16 x 79

    // Layer 1: H1 = x @ W1 (fp16 MFMA, BK=32, dbuf)
    mfma_gemm_kernel<0><<<gMf, 256, 0, stream>>>(xh, W1t, Hbuf, nullptr,
                                                 NNODES, IN_DIM, HC, 1);
    attn_kernel<<<NNODES, 256, 0, stream>>>(Hbuf, a_src1, a_dst1, as1, ad1);
    agg_kernel<0><<<MPAD, 256, 0, stream>>>(Hbuf, as1, ad1, b1, indptr, sorted, ei, A2);

    // Layer 2: H2 = elu_agg @ W2 (fp16 MFMA, BK=32, dbuf)
    mfma_gemm_kernel<0><<<gMf, 256, 0, stream>>>(A2, W2t, Hbuf, nullptr,
                                                 NNODES, HC, HC, 1);
    attn_kernel<<<NNODES, 256, 0, stream>>>(Hbuf, a_src2, a_dst2, as2, ad2);
    agg_kernel<1><<<MPAD, 256, 0, stream>>>(Hbuf, as2, ad2, b2, indptr, sorted, ei, out2h);

    // Projection + ReLU (fp16 MFMA, bias+relu fp32 epilogue)
    dim3 gProj(HID / 128, MPAD / 128);   // 2 x 79
    mfma_gemm_kernel<1><<<gProj, 256, 0, stream>>>(out2h, Wpt, out, bp,
                                                   NNODES, HID, HID, 0);
}